// Round 1
// baseline (130.339 us; speedup 1.0000x reference)
//
#include <hip/hip_runtime.h>
#include <hip/hip_bf16.h>

// Problem constants (fixed by the reference setup)
#define NMOL 1024
#define MOLSIZE 128
#define NPAIR_LOCAL (MOLSIZE * MOLSIZE)   // 16384 candidate pairs / molecule

// Output layout (all float32, concatenated in reference return order):
//   [0]                      nmol
//   [1]                      molsize
//   [2      .. 2+1024)       nHeavy
//   [1026   .. 2050)         nHydro
//   [2050   .. 3074)         nocc
//   [3074            .. +n_real)    Z
//   [3074+n_real     .. +n_real)    maskd
//   [3074+2*n_real   .. +n_real)    atom_molid
//   [P=3074+3*n_real .. +np)        mask
//   [P+np   ...]                    pair_molid, ni, nj, idxi, idxj
//   [P+6np  .. +3np)                xij (row-major, 3 per pair)
//   [P+9np  .. +np)                 rij

// ---------- K1: per-molecule stats ----------
__global__ void k_mol_stats(const int* __restrict__ species,
                            const float* __restrict__ tore,
                            float* __restrict__ out,
                            int* __restrict__ cnt_real) {
    __shared__ int shH[MOLSIZE], shY[MOLSIZE], shN[MOLSIZE];
    __shared__ float shT[MOLSIZE];
    int m = blockIdx.x, t = threadIdx.x;
    int s = species[m * MOLSIZE + t];
    shH[t] = (s > 1) ? 1 : 0;
    shY[t] = (s == 1) ? 1 : 0;
    shN[t] = (s > 0) ? 1 : 0;
    shT[t] = tore[s];
    __syncthreads();
    for (int d = MOLSIZE / 2; d > 0; d >>= 1) {
        if (t < d) {
            shH[t] += shH[t + d];
            shY[t] += shY[t + d];
            shN[t] += shN[t + d];
            shT[t] += shT[t + d];
        }
        __syncthreads();
    }
    if (t == 0) {
        out[2 + m] = (float)shH[0];
        out[2 + NMOL + m] = (float)shY[0];
        out[2 + 2 * NMOL + m] = (float)((int)(shT[0] * 0.5f));  // truncation, exact
        cnt_real[m] = shN[0];
        if (m == 0) { out[0] = (float)NMOL; out[1] = (float)MOLSIZE; }
    }
}

// ---------- Exclusive scan of 1024 ints, single block of 256 threads ----------
__global__ void k_scan1024(const int* __restrict__ cnt, int* __restrict__ base) {
    __shared__ int sums[256];
    int t = threadIdx.x;
    int v0 = cnt[t * 4 + 0], v1 = cnt[t * 4 + 1], v2 = cnt[t * 4 + 2], v3 = cnt[t * 4 + 3];
    sums[t] = v0 + v1 + v2 + v3;
    __syncthreads();
    // Hillis-Steele inclusive scan over 256 thread sums
    for (int d = 1; d < 256; d <<= 1) {
        int x = (t >= d) ? sums[t - d] : 0;
        __syncthreads();
        sums[t] += x;
        __syncthreads();
    }
    int excl = (t == 0) ? 0 : sums[t - 1];
    base[t * 4 + 0] = excl;
    base[t * 4 + 1] = excl + v0;
    base[t * 4 + 2] = excl + v0 + v1;
    base[t * 4 + 3] = excl + v0 + v1 + v2;
    if (t == 255) base[1024] = sums[255];  // total
}

// ---------- K3: stable atom compaction + Z/maskd/atom_molid ----------
__global__ void k_atom_scatter(const int* __restrict__ species,
                               const int* __restrict__ mol_base,
                               int* __restrict__ inv_real,
                               float* __restrict__ out) {
    int m = blockIdx.x, t = threadIdx.x;
    int f = m * MOLSIZE + t;
    int s = species[f];
    bool nb = (s > 0);
    int lane = t & 63, wave = t >> 6;
    unsigned long long mb = __ballot(nb);
    __shared__ int wcnt[2];
    if (lane == 0) wcnt[wave] = __popcll(mb);
    __syncthreads();
    if (nb) {
        int g = mol_base[m] + ((wave == 1) ? wcnt[0] : 0) +
                __popcll(mb & ((1ull << lane) - 1ull));
        inv_real[f] = g;
        int n_real = mol_base[NMOL];
        out[3074 + g] = (float)s;
        out[3074 + n_real + g] = (float)(t * (MOLSIZE + 1) + m * (MOLSIZE * MOLSIZE));
        out[3074 + 2 * n_real + g] = (float)m;
    }
}

// Exact-reference distance predicate: f32 sub, (x^2+y^2)+z^2 no-fma, sqrt, < 5.0
__device__ __forceinline__ bool pair_pred(float ax, float ay, float az,
                                          float bx, float by, float bz,
                                          float& dx, float& dy, float& dz, float& dist) {
    dx = __fsub_rn(bx, ax);
    dy = __fsub_rn(by, ay);
    dz = __fsub_rn(bz, az);
    float d2 = __fadd_rn(__fadd_rn(__fmul_rn(dx, dx), __fmul_rn(dy, dy)), __fmul_rn(dz, dz));
    dist = __fsqrt_rn(d2);
    return dist < 5.0f;
}

// ---------- K4: per-molecule pair count ----------
__global__ __launch_bounds__(256) void k_pair_count(const int* __restrict__ species,
                                                    const float* __restrict__ coord,
                                                    int* __restrict__ pair_cnt) {
    __shared__ float cx[MOLSIZE], cy[MOLSIZE], cz[MOLSIZE];
    __shared__ int sp[MOLSIZE];
    __shared__ int red[256];
    int m = blockIdx.x, t = threadIdx.x;
    if (t < MOLSIZE) {
        int f = m * MOLSIZE + t;
        sp[t] = species[f];
        cx[t] = coord[f * 3 + 0];
        cy[t] = coord[f * 3 + 1];
        cz[t] = coord[f * 3 + 2];
    }
    __syncthreads();
    int cnt = 0;
    for (int p = t; p < NPAIR_LOCAL; p += 256) {
        int a = p >> 7, b = p & (MOLSIZE - 1);
        if (a < b && sp[a] > 0 && sp[b] > 0) {
            float dx, dy, dz, dist;
            if (pair_pred(cx[a], cy[a], cz[a], cx[b], cy[b], cz[b], dx, dy, dz, dist)) cnt++;
        }
    }
    red[t] = cnt;
    __syncthreads();
    for (int d = 128; d > 0; d >>= 1) {
        if (t < d) red[t] += red[t + d];
        __syncthreads();
    }
    if (t == 0) pair_cnt[m] = red[0];
}

// ---------- K6: stable pair compaction + all pair outputs ----------
__global__ __launch_bounds__(256) void k_pair_scatter(const int* __restrict__ species,
                                                      const float* __restrict__ coord,
                                                      const int* __restrict__ inv_real,
                                                      const int* __restrict__ mol_base,
                                                      const int* __restrict__ pair_base,
                                                      float* __restrict__ out) {
    __shared__ float cx[MOLSIZE], cy[MOLSIZE], cz[MOLSIZE];
    __shared__ int sp[MOLSIZE], iv[MOLSIZE];
    __shared__ int wsum[4];
    int m = blockIdx.x, t = threadIdx.x;
    if (t < MOLSIZE) {
        int f = m * MOLSIZE + t;
        sp[t] = species[f];
        iv[t] = inv_real[f];
        cx[t] = coord[f * 3 + 0];
        cy[t] = coord[f * 3 + 1];
        cz[t] = coord[f * 3 + 2];
    }
    __syncthreads();
    int n_real = mol_base[NMOL];
    int npairs = pair_base[NMOL];
    long long offP = 3074LL + 3LL * n_real;
    int base = pair_base[m];
    int lane = t & 63, wave = t >> 6;
    for (int it = 0; it < NPAIR_LOCAL / 256; ++it) {
        int p = it * 256 + t;  // ascending p <=> (it, wave, lane) lexicographic: stable
        int a = p >> 7, b = p & (MOLSIZE - 1);
        bool ok = false;
        float dx = 0.f, dy = 0.f, dz = 0.f, dist = 0.f;
        if (a < b && sp[a] > 0 && sp[b] > 0)
            ok = pair_pred(cx[a], cy[a], cz[a], cx[b], cy[b], cz[b], dx, dy, dz, dist);
        unsigned long long mb = __ballot(ok);
        if (lane == 0) wsum[wave] = __popcll(mb);
        __syncthreads();
        int prefix = 0, total = 0;
        for (int w = 0; w < 4; ++w) {
            int c = wsum[w];
            if (w < wave) prefix += c;
            total += c;
        }
        if (ok) {
            int rank = __popcll(mb & ((1ull << lane) - 1ull));
            long long q = base + prefix + rank;
            out[offP + q] = (float)((m * MOLSIZE + a) * MOLSIZE + b);          // mask
            out[offP + 1LL * npairs + q] = (float)m;                            // pair_molid
            out[offP + 2LL * npairs + q] = (float)sp[a];                        // ni
            out[offP + 3LL * npairs + q] = (float)sp[b];                        // nj
            out[offP + 4LL * npairs + q] = (float)iv[a];                        // idxi
            out[offP + 5LL * npairs + q] = (float)iv[b];                        // idxj
            long long xo = offP + 6LL * npairs + 3LL * q;
            out[xo + 0] = __fdiv_rn(dx, dist);                                  // xij
            out[xo + 1] = __fdiv_rn(dy, dist);
            out[xo + 2] = __fdiv_rn(dz, dist);
            out[offP + 9LL * npairs + q] = __fmul_rn(dist, 1.8897261258369282f);// rij
        }
        base += total;
        __syncthreads();  // protect wsum before next iteration's write
    }
}

extern "C" void kernel_launch(void* const* d_in, const int* in_sizes, int n_in,
                              void* d_out, int out_size, void* d_ws, size_t ws_size,
                              hipStream_t stream) {
    const int* species = (const int*)d_in[0];
    const float* coords = (const float*)d_in[1];
    const float* tore = (const float*)d_in[2];
    float* out = (float*)d_out;
    int* ws = (int*)d_ws;

    int* cnt_real  = ws;               // 1024
    int* mol_base  = ws + 1024;        // 1025 (last = n_real)
    int* pair_cnt  = ws + 2049;        // 1024
    int* pair_base = ws + 3073;        // 1025 (last = npairs)
    int* inv_real  = ws + 4098;        // 131072

    k_mol_stats<<<NMOL, MOLSIZE, 0, stream>>>(species, tore, out, cnt_real);
    k_scan1024<<<1, 256, 0, stream>>>(cnt_real, mol_base);
    k_atom_scatter<<<NMOL, MOLSIZE, 0, stream>>>(species, mol_base, inv_real, out);
    k_pair_count<<<NMOL, 256, 0, stream>>>(species, coords, pair_cnt);
    k_scan1024<<<1, 256, 0, stream>>>(pair_cnt, pair_base);
    k_pair_scatter<<<NMOL, 256, 0, stream>>>(species, coords, inv_real, mol_base, pair_base, out);
}

// Round 2
// 99.600 us; speedup vs baseline: 1.3086x; 1.3086x over previous
//
#include <hip/hip_runtime.h>
#include <hip/hip_bf16.h>

#define NMOL 1024
#define MOLSIZE 128

// Output layout (all float32, reference return order, flat):
// [0] nmol, [1] molsize, [2..2+1024) nHeavy, [1026..2050) nHydro, [2050..3074) nocc,
// [3074 +0/1/2*n_real) Z, maskd, atom_molid,
// P=3074+3*n_real: mask, pair_molid, ni, nj, idxi, idxj (np each), xij (3*np), rij (np)

// Exact-reference arithmetic: f32 sub, (x^2+y^2)+z^2 without fma, sqrt, compare.
__device__ __forceinline__ float pair_dist(float ax, float ay, float az,
                                           float bx, float by, float bz,
                                           float& dx, float& dy, float& dz) {
    dx = __fsub_rn(bx, ax);
    dy = __fsub_rn(by, ay);
    dz = __fsub_rn(bz, az);
    float d2 = __fadd_rn(__fadd_rn(__fmul_rn(dx, dx), __fmul_rn(dy, dy)), __fmul_rn(dz, dz));
    return __fsqrt_rn(d2);
}

// ---------- K1: mol stats + per-chunk pair counts (chunk = 64 consecutive p) ----------
__global__ __launch_bounds__(256) void k_count(const int* __restrict__ species,
                                               const float* __restrict__ coord,
                                               const float* __restrict__ tore,
                                               float* __restrict__ out,
                                               int* __restrict__ cnt_real,
                                               int* __restrict__ pair_tot,
                                               unsigned char* __restrict__ chunk_cnt) {
    __shared__ float cx[MOLSIZE], cy[MOLSIZE], cz[MOLSIZE];
    __shared__ int rH[MOLSIZE], rY[MOLSIZE], rN[MOLSIZE];
    __shared__ float rT[MOLSIZE];
    __shared__ int wpair[4];
    int m = blockIdx.x, t = threadIdx.x;
    if (t < MOLSIZE) {
        int f = m * MOLSIZE + t;
        int s = species[f];
        bool nb = (s > 0);
        float x = coord[f * 3 + 0], y = coord[f * 3 + 1], z = coord[f * 3 + 2];
        float sent = 1.0e30f * (float)(t + 1);  // distinct sentinel: blank-blank diff >= 1e30 -> d2 = inf
        cx[t] = nb ? x : sent;
        cy[t] = nb ? y : sent;
        cz[t] = nb ? z : sent;
        rH[t] = (s > 1) ? 1 : 0;
        rY[t] = (s == 1) ? 1 : 0;
        rN[t] = nb ? 1 : 0;
        rT[t] = tore[s];
    }
    __syncthreads();
    for (int d = 64; d > 0; d >>= 1) {
        if (t < d) { rH[t] += rH[t + d]; rY[t] += rY[t + d]; rN[t] += rN[t + d]; rT[t] += rT[t + d]; }
        __syncthreads();
    }
    if (t == 0) {
        out[2 + m] = (float)rH[0];
        out[2 + NMOL + m] = (float)rY[0];
        out[2 + 2 * NMOL + m] = (float)((int)(rT[0] * 0.5f));
        cnt_real[m] = rN[0];
        if (m == 0) { out[0] = (float)NMOL; out[1] = (float)MOLSIZE; }
    }
    // pair counting: wave w handles rows a = w, w+4, ...; chunk id = 2a + (b>=64)
    int lane = t & 63, w = t >> 6;
    float bxl = cx[lane], byl = cy[lane], bzl = cz[lane];
    float bxh = cx[64 + lane], byh = cy[64 + lane], bzh = cz[64 + lane];
    unsigned char* cc = chunk_cnt + m * 256;
    int wcount = 0;
    for (int j = 0; j < 32; ++j) {
        int a = w + 4 * j;
        float ax = cx[a], ay = cy[a], az = cz[a];  // broadcast
        int c0 = 0, c1 = 0;
        if (a < 63) {  // lo half: b = lane, need b > a
            float dx, dy, dz;
            float dist = pair_dist(ax, ay, az, bxl, byl, bzl, dx, dy, dz);
            bool ok = (lane > a) && (dist < 5.0f);
            c0 = __popcll(__ballot(ok));
        }
        if (a < 127) {  // hi half: b = 64+lane
            float dx, dy, dz;
            float dist = pair_dist(ax, ay, az, bxh, byh, bzh, dx, dy, dz);
            bool ok = ((64 + lane) > a) && (dist < 5.0f);
            c1 = __popcll(__ballot(ok));
        }
        if (lane == 0) { cc[2 * a] = (unsigned char)c0; cc[2 * a + 1] = (unsigned char)c1; }
        wcount += c0 + c1;
    }
    if (lane == 0) wpair[w] = wcount;
    __syncthreads();
    if (t == 0) pair_tot[m] = wpair[0] + wpair[1] + wpair[2] + wpair[3];
}

// ---------- K2: two independent 1024-element exclusive scans (block 0: atoms, block 1: pairs) ----------
__global__ void k_scan2(const int* __restrict__ cnt_real, const int* __restrict__ pair_tot,
                        int* __restrict__ mol_base, int* __restrict__ pair_mol_base) {
    const int* cnt = blockIdx.x ? pair_tot : cnt_real;
    int* base = blockIdx.x ? pair_mol_base : mol_base;
    __shared__ int sums[256];
    int t = threadIdx.x;
    int v0 = cnt[t * 4 + 0], v1 = cnt[t * 4 + 1], v2 = cnt[t * 4 + 2], v3 = cnt[t * 4 + 3];
    sums[t] = v0 + v1 + v2 + v3;
    __syncthreads();
    for (int d = 1; d < 256; d <<= 1) {
        int x = (t >= d) ? sums[t - d] : 0;
        __syncthreads();
        sums[t] += x;
        __syncthreads();
    }
    int excl = (t == 0) ? 0 : sums[t - 1];
    base[t * 4 + 0] = excl;
    base[t * 4 + 1] = excl + v0;
    base[t * 4 + 2] = excl + v0 + v1;
    base[t * 4 + 3] = excl + v0 + v1 + v2;
    if (t == 255) base[1024] = sums[255];
}

// ---------- K3: atom outputs + pair scatter (no barriers in hot loop) ----------
__global__ __launch_bounds__(256) void k_scatter(const int* __restrict__ species,
                                                 const float* __restrict__ coord,
                                                 const int* __restrict__ mol_base,
                                                 const int* __restrict__ pair_mol_base,
                                                 const unsigned char* __restrict__ chunk_cnt,
                                                 float* __restrict__ out) {
    __shared__ float cx[MOLSIZE], cy[MOLSIZE], cz[MOLSIZE];
    __shared__ int sp[MOLSIZE], iv[MOLSIZE];
    __shared__ int scan[256];
    __shared__ int cbase[256];
    __shared__ int wc0s;
    int m = blockIdx.x, t = threadIdx.x;
    int n_real = mol_base[NMOL];
    int npairs = pair_mol_base[NMOL];
    int lane = t & 63, w = t >> 6;
    int cval = (int)chunk_cnt[m * 256 + t];

    unsigned long long amb = 0ull;
    int s_at = 0;
    if (t < MOLSIZE) {
        int f = m * MOLSIZE + t;
        s_at = species[f];
        bool nb = (s_at > 0);
        float x = coord[f * 3 + 0], y = coord[f * 3 + 1], z = coord[f * 3 + 2];
        float sent = 1.0e30f * (float)(t + 1);
        cx[t] = nb ? x : sent;
        cy[t] = nb ? y : sent;
        cz[t] = nb ? z : sent;
        sp[t] = s_at;
        amb = __ballot(nb);
        if (t == 0) wc0s = __popcll(amb);
    }
    // chunk-count scan (Hillis-Steele over 256), also provides the barrier for wc0s/LDS
    scan[t] = cval;
    __syncthreads();
    for (int d = 1; d < 256; d <<= 1) {
        int x = (t >= d) ? scan[t - d] : 0;
        __syncthreads();
        scan[t] += x;
        __syncthreads();
    }
    cbase[t] = pair_mol_base[m] + scan[t] - cval;  // exclusive + molecule base
    // atom outputs
    if (t < MOLSIZE && s_at > 0) {
        int rank = __popcll(amb & ((1ull << lane) - 1ull)) + ((w == 1) ? wc0s : 0);
        int g = mol_base[m] + rank;
        iv[t] = g;
        out[3074 + g] = (float)s_at;
        out[3074 + n_real + g] = (float)(t * (MOLSIZE + 1) + m * (MOLSIZE * MOLSIZE));
        out[3074 + 2 * n_real + g] = (float)m;
    }
    __syncthreads();  // iv + cbase visible

    // register-resident b-atom data
    float bxl = cx[lane], byl = cy[lane], bzl = cz[lane];
    float bxh = cx[64 + lane], byh = cy[64 + lane], bzh = cz[64 + lane];
    int ivl = iv[lane], ivh = iv[64 + lane];
    float fsl = (float)sp[lane], fsh = (float)sp[64 + lane];
    float fm = (float)m;
    int offP = 3074 + 3 * n_real;
    float* pm0 = out + offP;                 // mask
    float* pm1 = pm0 + npairs;               // pair_molid
    float* pm2 = pm1 + npairs;               // ni
    float* pm3 = pm2 + npairs;               // nj
    float* pm4 = pm3 + npairs;               // idxi
    float* pm5 = pm4 + npairs;               // idxj
    float* px  = pm5 + npairs;               // xij (3 per pair) -- raw dx,dy,dz here
    float* pr  = px + 3 * npairs;            // rij -- raw dist here

    for (int j = 0; j < 32; ++j) {
        int a = w + 4 * j;
        float ax = cx[a], ay = cy[a], az = cz[a];
        int iva = iv[a];
        float fsa = (float)sp[a];
        int mrow = m * (MOLSIZE * MOLSIZE) + a * MOLSIZE;
        if (a < 63) {
            float dx, dy, dz;
            float dist = pair_dist(ax, ay, az, bxl, byl, bzl, dx, dy, dz);
            bool ok = (lane > a) && (dist < 5.0f);
            unsigned long long mb = __ballot(ok);
            if (ok) {
                int q = cbase[2 * a] + __popcll(mb & ((1ull << lane) - 1ull));
                pm0[q] = (float)(mrow + lane);
                pm1[q] = fm;
                pm2[q] = fsa;
                pm3[q] = fsl;
                pm4[q] = (float)iva;
                pm5[q] = (float)ivl;
                px[3 * q + 0] = dx;
                px[3 * q + 1] = dy;
                px[3 * q + 2] = dz;
                pr[q] = dist;
            }
        }
        if (a < 127) {
            float dx, dy, dz;
            float dist = pair_dist(ax, ay, az, bxh, byh, bzh, dx, dy, dz);
            bool ok = ((64 + lane) > a) && (dist < 5.0f);
            unsigned long long mb = __ballot(ok);
            if (ok) {
                int q = cbase[2 * a + 1] + __popcll(mb & ((1ull << lane) - 1ull));
                pm0[q] = (float)(mrow + 64 + lane);
                pm1[q] = fm;
                pm2[q] = fsa;
                pm3[q] = fsh;
                pm4[q] = (float)iva;
                pm5[q] = (float)ivh;
                px[3 * q + 0] = dx;
                px[3 * q + 1] = dy;
                px[3 * q + 2] = dz;
                pr[q] = dist;
            }
        }
    }
}

// ---------- K4: dense division/scale fixup over compacted pairs ----------
__global__ __launch_bounds__(256) void k_fix(const int* __restrict__ mol_base,
                                             const int* __restrict__ pair_mol_base,
                                             float* __restrict__ out) {
    int n_real = mol_base[NMOL];
    int npairs = pair_mol_base[NMOL];
    int offP = 3074 + 3 * n_real;
    float* px = out + offP + 6 * npairs;
    float* pr = out + offP + 9 * npairs;
    for (int q = blockIdx.x * 256 + threadIdx.x; q < npairs; q += gridDim.x * 256) {
        float dist = pr[q];
        float dx = px[3 * q + 0], dy = px[3 * q + 1], dz = px[3 * q + 2];
        px[3 * q + 0] = __fdiv_rn(dx, dist);
        px[3 * q + 1] = __fdiv_rn(dy, dist);
        px[3 * q + 2] = __fdiv_rn(dz, dist);
        pr[q] = __fmul_rn(dist, 1.8897261258369282f);
    }
}

extern "C" void kernel_launch(void* const* d_in, const int* in_sizes, int n_in,
                              void* d_out, int out_size, void* d_ws, size_t ws_size,
                              hipStream_t stream) {
    const int* species = (const int*)d_in[0];
    const float* coords = (const float*)d_in[1];
    const float* tore = (const float*)d_in[2];
    float* out = (float*)d_out;
    int* ws = (int*)d_ws;

    int* cnt_real      = ws;            // 1024
    int* pair_tot      = ws + 1024;     // 1024
    int* mol_base      = ws + 2048;     // 1025
    int* pair_mol_base = ws + 3073;     // 1025
    unsigned char* chunk_cnt = (unsigned char*)(ws + 4100);  // 1024*256 bytes

    k_count<<<NMOL, 256, 0, stream>>>(species, coords, tore, out, cnt_real, pair_tot, chunk_cnt);
    k_scan2<<<2, 256, 0, stream>>>(cnt_real, pair_tot, mol_base, pair_mol_base);
    k_scatter<<<NMOL, 256, 0, stream>>>(species, coords, mol_base, pair_mol_base, chunk_cnt, out);
    k_fix<<<1024, 256, 0, stream>>>(mol_base, pair_mol_base, out);
}

// Round 4
// 81.298 us; speedup vs baseline: 1.6032x; 1.2251x over previous
//
#include <hip/hip_runtime.h>
#include <hip/hip_bf16.h>

#define NMOL 1024
#define MOLSIZE 128

// Output layout (all float32, reference return order, flat):
// [0] nmol, [1] molsize, [2..2+1024) nHeavy, [1026..2050) nHydro, [2050..3074) nocc,
// [3074 +0/1/2*n_real) Z, maskd, atom_molid,
// P=3074+3*n_real: mask, pair_molid, ni, nj, idxi, idxj (np each), xij (3*np), rij (np)

// Exact-reference arithmetic: f32 sub, (x^2+y^2)+z^2 without fma, sqrt.
__device__ __forceinline__ float pair_dist(float ax, float ay, float az,
                                           float bx, float by, float bz,
                                           float& dx, float& dy, float& dz) {
    dx = __fsub_rn(bx, ax);
    dy = __fsub_rn(by, ay);
    dz = __fsub_rn(bz, az);
    float d2 = __fadd_rn(__fadd_rn(__fmul_rn(dx, dx), __fmul_rn(dy, dy)), __fmul_rn(dz, dz));
    return __fsqrt_rn(d2);
}

// ---------- K1: mol stats + per-chunk ballots (chunk c = 2*a + (b>=64), bit = b&63) ----------
__global__ __launch_bounds__(256) void k_count(const int* __restrict__ species,
                                               const float* __restrict__ coord,
                                               const float* __restrict__ tore,
                                               float* __restrict__ out,
                                               int* __restrict__ cnt_real,
                                               int* __restrict__ pair_tot,
                                               unsigned long long* __restrict__ bal_g) {
    __shared__ float cx[MOLSIZE], cy[MOLSIZE], cz[MOLSIZE];
    __shared__ unsigned long long bal_s[256];
    __shared__ int sH[2], sY[2], sN[2];
    __shared__ float sT[2];
    __shared__ int wpair[4];
    int m = blockIdx.x, t = threadIdx.x;
    int lane = t & 63, w = t >> 6;
    if (t < MOLSIZE) {
        int f = m * MOLSIZE + t;
        int s = species[f];
        bool nb = (s > 0);
        float x = coord[f * 3 + 0], y = coord[f * 3 + 1], z = coord[f * 3 + 2];
        float sent = 1.0e30f * (float)(t + 1);  // blanks -> dist = inf
        cx[t] = nb ? x : sent;
        cy[t] = nb ? y : sent;
        cz[t] = nb ? z : sent;
        int h = (s > 1) ? 1 : 0, yy = (s == 1) ? 1 : 0, nn = nb ? 1 : 0;
        float tv = tore[s];  // integer-valued: all reduction orders exact
        for (int d = 32; d > 0; d >>= 1) {
            h += __shfl_down(h, d);
            yy += __shfl_down(yy, d);
            nn += __shfl_down(nn, d);
            tv += __shfl_down(tv, d);
        }
        if (lane == 0) { sH[w] = h; sY[w] = yy; sN[w] = nn; sT[w] = tv; }
    }
    __syncthreads();
    if (t == 0) {
        out[2 + m] = (float)(sH[0] + sH[1]);
        out[2 + NMOL + m] = (float)(sY[0] + sY[1]);
        out[2 + 2 * NMOL + m] = (float)((int)((sT[0] + sT[1]) * 0.5f));
        cnt_real[m] = sN[0] + sN[1];
        if (m == 0) { out[0] = (float)NMOL; out[1] = (float)MOLSIZE; }
    }
    // pair sweep: wave w handles rows a = w, w+4, ...
    float bxl = cx[lane], byl = cy[lane], bzl = cz[lane];
    float bxh = cx[64 + lane], byh = cy[64 + lane], bzh = cz[64 + lane];
    int wcount = 0;
    for (int j = 0; j < 32; ++j) {
        int a = w + 4 * j;
        float ax = cx[a], ay = cy[a], az = cz[a];  // broadcast reads
        unsigned long long mb0 = 0ull, mb1 = 0ull;
        if (a < 63) {  // lo half: b = lane, need b > a
            float dx, dy, dz;
            float dist = pair_dist(ax, ay, az, bxl, byl, bzl, dx, dy, dz);
            mb0 = __ballot((lane > a) && (dist < 5.0f));
        }
        if (a < 127) {  // hi half: b = 64+lane, need b > a (matters for a >= 64!)
            float dx, dy, dz;
            float dist = pair_dist(ax, ay, az, bxh, byh, bzh, dx, dy, dz);
            mb1 = __ballot(((64 + lane) > a) && (dist < 5.0f));
        }
        if (lane == 0) { bal_s[2 * a] = mb0; bal_s[2 * a + 1] = mb1; }
        wcount += __popcll(mb0) + __popcll(mb1);
    }
    if (lane == 0) wpair[w] = wcount;
    __syncthreads();
    if (t == 0) pair_tot[m] = wpair[0] + wpair[1] + wpair[2] + wpair[3];
    bal_g[m * 256 + t] = bal_s[t];  // coalesced 2KB store
}

// ---------- K2: two independent 1024-element exclusive scans ----------
__global__ void k_scan2(const int* __restrict__ cnt_real, const int* __restrict__ pair_tot,
                        int* __restrict__ mol_base, int* __restrict__ pair_mol_base) {
    const int* cnt = blockIdx.x ? pair_tot : cnt_real;
    int* base = blockIdx.x ? pair_mol_base : mol_base;
    __shared__ int wt[4];
    int t = threadIdx.x, lane = t & 63, w = t >> 6;
    int v0 = cnt[t * 4 + 0], v1 = cnt[t * 4 + 1], v2 = cnt[t * 4 + 2], v3 = cnt[t * 4 + 3];
    int s = v0 + v1 + v2 + v3;
    int v = s;
    for (int d = 1; d < 64; d <<= 1) {
        int u = __shfl_up(v, d);
        if (lane >= d) v += u;
    }
    if (lane == 63) wt[w] = v;
    __syncthreads();
    int add = 0;
    for (int ww = 0; ww < w; ++ww) add += wt[ww];
    int incl = v + add;
    int excl = incl - s;
    base[t * 4 + 0] = excl;
    base[t * 4 + 1] = excl + v0;
    base[t * 4 + 2] = excl + v0 + v1;
    base[t * 4 + 3] = excl + v0 + v1 + v2;
    if (t == 255) base[1024] = incl;
}

// ---------- K3: atom outputs + dense pair scatter from ballots ----------
__global__ __launch_bounds__(256) void k_scatter(const int* __restrict__ species,
                                                 const float* __restrict__ coord,
                                                 const int* __restrict__ mol_base,
                                                 const int* __restrict__ pair_mol_base,
                                                 const unsigned long long* __restrict__ bal_g,
                                                 float* __restrict__ out) {
    __shared__ float cx[MOLSIZE], cy[MOLSIZE], cz[MOLSIZE], spf[MOLSIZE];
    __shared__ int iv[MOLSIZE];
    __shared__ unsigned long long bal_s[256];
    __shared__ int sIncl[256];
    __shared__ int wtot[4];
    __shared__ int wc0s;
    int m = blockIdx.x, t = threadIdx.x;
    int lane = t & 63, w = t >> 6;
    int n_real = mol_base[NMOL];
    int npairs = pair_mol_base[NMOL];

    unsigned long long bal = bal_g[m * 256 + t];
    bal_s[t] = bal;
    int cval = __popcll(bal);

    int s_at = 0;
    unsigned long long amb = 0ull;
    if (t < MOLSIZE) {
        int f = m * MOLSIZE + t;
        s_at = species[f];
        cx[t] = coord[f * 3 + 0];
        cy[t] = coord[f * 3 + 1];
        cz[t] = coord[f * 3 + 2];
        spf[t] = (float)s_at;
        amb = __ballot(s_at > 0);
        if (t == 0) wc0s = __popcll(amb);
    }
    // wave-level inclusive scan of chunk counts
    int v = cval;
    for (int d = 1; d < 64; d <<= 1) {
        int u = __shfl_up(v, d);
        if (lane >= d) v += u;
    }
    if (lane == 63) wtot[w] = v;
    __syncthreads();
    // atom outputs (reads wc0s after barrier)
    if (t < MOLSIZE && s_at > 0) {
        int rank = __popcll(amb & ((1ull << lane) - 1ull)) + ((w == 1) ? wc0s : 0);
        int g = mol_base[m] + rank;
        iv[t] = g;
        out[3074 + g] = (float)s_at;
        out[3074 + n_real + g] = (float)(t * (MOLSIZE + 1) + m * (MOLSIZE * MOLSIZE));
        out[3074 + 2 * n_real + g] = (float)m;
    }
    int add = 0;
    for (int ww = 0; ww < w; ++ww) add += wtot[ww];
    int np_mol = wtot[0] + wtot[1] + wtot[2] + wtot[3];
    sIncl[t] = v + add;
    __syncthreads();  // iv, sIncl visible

    int offP = 3074 + 3 * n_real;
    float* pm0 = out + offP;
    float* pm1 = pm0 + npairs;
    float* pm2 = pm1 + npairs;
    float* pm3 = pm2 + npairs;
    float* pm4 = pm3 + npairs;
    float* pm5 = pm4 + npairs;
    float* px  = pm5 + npairs;
    float* pr  = px + 3 * npairs;
    int qbase = pair_mol_base[m];
    float fm = (float)m;

    for (int q = t; q < np_mol; q += 256) {
        // binary search: c = first chunk with inclusive-scan > q
        int c = 0;
        if (sIncl[c + 127] <= q) c += 128;
        if (sIncl[c + 63] <= q) c += 64;
        if (sIncl[c + 31] <= q) c += 32;
        if (sIncl[c + 15] <= q) c += 16;
        if (sIncl[c + 7] <= q) c += 8;
        if (sIncl[c + 3] <= q) c += 4;
        if (sIncl[c + 1] <= q) c += 2;
        if (sIncl[c] <= q) c += 1;
        int r = q - (c ? sIncl[c - 1] : 0);
        unsigned long long mb = bal_s[c];
        // branchless select of r-th set bit
        unsigned int cur = (unsigned int)mb;
        int idx = 0;
        int cc = __popc(cur);
        if (r >= cc) { r -= cc; idx = 32; cur = (unsigned int)(mb >> 32); }
        cc = __popc(cur & 0xFFFFu); if (r >= cc) { r -= cc; idx += 16; cur >>= 16; }
        cc = __popc(cur & 0xFFu);   if (r >= cc) { r -= cc; idx += 8;  cur >>= 8; }
        cc = __popc(cur & 0xFu);    if (r >= cc) { r -= cc; idx += 4;  cur >>= 4; }
        cc = __popc(cur & 0x3u);    if (r >= cc) { r -= cc; idx += 2;  cur >>= 2; }
        cc = cur & 1u;              if (r >= cc) { idx += 1; }
        int a = c >> 1;
        int b = ((c & 1) << 6) | idx;
        float dx, dy, dz;
        float dist = pair_dist(cx[a], cy[a], cz[a], cx[b], cy[b], cz[b], dx, dy, dz);
        int Q = qbase + q;
        pm0[Q] = (float)(m * (MOLSIZE * MOLSIZE) + a * MOLSIZE + b);
        pm1[Q] = fm;
        pm2[Q] = spf[a];
        pm3[Q] = spf[b];
        pm4[Q] = (float)iv[a];
        pm5[Q] = (float)iv[b];
        px[3 * Q + 0] = __fdiv_rn(dx, dist);
        px[3 * Q + 1] = __fdiv_rn(dy, dist);
        px[3 * Q + 2] = __fdiv_rn(dz, dist);
        pr[Q] = __fmul_rn(dist, 1.8897261258369282f);
    }
}

extern "C" void kernel_launch(void* const* d_in, const int* in_sizes, int n_in,
                              void* d_out, int out_size, void* d_ws, size_t ws_size,
                              hipStream_t stream) {
    const int* species = (const int*)d_in[0];
    const float* coords = (const float*)d_in[1];
    const float* tore = (const float*)d_in[2];
    float* out = (float*)d_out;
    int* ws = (int*)d_ws;

    int* cnt_real      = ws;            // 1024
    int* pair_tot      = ws + 1024;     // 1024
    int* mol_base      = ws + 2048;     // 1025
    int* pair_mol_base = ws + 3073;     // 1025
    unsigned long long* bal_g = (unsigned long long*)(ws + 4100);  // 1024*256*8 B = 2 MB

    k_count<<<NMOL, 256, 0, stream>>>(species, coords, tore, out, cnt_real, pair_tot, bal_g);
    k_scan2<<<2, 256, 0, stream>>>(cnt_real, pair_tot, mol_base, pair_mol_base);
    k_scatter<<<NMOL, 256, 0, stream>>>(species, coords, mol_base, pair_mol_base, bal_g, out);
}